// Round 2
// baseline (468.504 us; speedup 1.0000x reference)
//
#include <hip/hip_runtime.h>
#include <stdint.h>

// Problem constants
#define B_   20
#define S_   4096
#define E_   256
#define NB_  32
#define M_   (B_ * S_)          // 81920 rows

// ws layout (bytes) — total ~168.3 MB
#define OFF_Q   41943040ull     // after xb/ob region (M*256*2)
#define OFF_K   83886080ull
#define OFF_V   125829120ull    // vT bf16 [B][E][S]
#define OFF_WT  167772160ull    // WqT,WkT,WvT,WoT bf16, 131072 B each

typedef __attribute__((ext_vector_type(4))) float f32x4;
typedef __attribute__((ext_vector_type(8))) short short8;   // 8 x bf16
typedef __attribute__((ext_vector_type(4))) float float4v;
typedef __attribute__((ext_vector_type(4))) unsigned short us4;

__device__ __forceinline__ unsigned short f2bf(float f) {
  unsigned int u = __builtin_bit_cast(unsigned int, f);
  u += 0x7FFFu + ((u >> 16) & 1u);            // RNE
  return (unsigned short)(u >> 16);
}

__device__ __forceinline__ void glds16(const void* g, void* l) {
  __builtin_amdgcn_global_load_lds(
      (const __attribute__((address_space(1))) unsigned int*)g,
      (__attribute__((address_space(3))) unsigned int*)l, 16, 0, 0);
}

// ---------------- K0a: x fp32 -> bf16 ----------------
__global__ void k_convert_x(const float* __restrict__ x, unsigned short* __restrict__ xb) {
  size_t id = (size_t)blockIdx.x * 256 + threadIdx.x;   // 5,242,880 threads, 4 elems each
  float4v v = *(const float4v*)(x + id * 4);
  us4 o;
  o[0] = f2bf(v[0]); o[1] = f2bf(v[1]); o[2] = f2bf(v[2]); o[3] = f2bf(v[3]);
  *(us4*)(xb + id * 4) = o;
}

// ---------------- K0b: weights fp32 -> bf16, TRANSPOSED ([n][k]) ----------------
__global__ void k_convert_w(const float* __restrict__ Wq, const float* __restrict__ Wk,
                            const float* __restrict__ Wv, const float* __restrict__ Wo,
                            unsigned short* __restrict__ WT) {
  const float* src = (blockIdx.x == 0) ? Wq : (blockIdx.x == 1) ? Wk
                   : (blockIdx.x == 2) ? Wv : Wo;
  unsigned short* dst = WT + (size_t)blockIdx.x * 65536;
  int n = threadIdx.x;                                   // output row = original col
  for (int k = 0; k < 256; ++k)
    dst[n * 256 + k] = f2bf(src[k * 256 + n]);           // coalesced read across threads
}

// ---------------- K1/K3: GEMM C = A(bf16,[M][256]) * W ( via WT[n][k] ) ----------------
// 128x128 tile, BK=64, 4 waves each 64x64 (4x4 of 16x16x32 frags).
// LDS tiles XOR-swizzled (byte ^= (row&7)<<4) via pre-swizzled global source (G21).
// For mat==2 (V) the epilogue writes TRANSPOSED into vT[b][feat][s] — fuses the
// V-transpose that the attention PV step needs (B-operand wants V^T rows).
template <bool QKV>
__global__ __launch_bounds__(256, 3) void k_gemm(const unsigned short* __restrict__ A,
                                                 const unsigned short* __restrict__ WT,
                                                 void* __restrict__ out,
                                                 unsigned short* __restrict__ vT,
                                                 const float* __restrict__ bias) {
  __shared__ char Alds[16384];
  __shared__ char Blds[16384];
  const int nct = QKV ? 6 : 2;
  int bx = blockIdx.x;
  int ct = bx % nct, rt = bx / nct;                                   // 6 col-tiles share one A tile
  int mat = QKV ? (ct >> 1) : 3;
  int col0 = (ct & 1) * 128;

  int tid = threadIdx.x, w = tid >> 6, l = tid & 63;
  int wr = (w >> 1) * 64, wc = (w & 1) * 64;
  int hi16 = (l >> 4) * 16;

  const char* Ab = (const char*)A + (size_t)rt * 128 * 512;           // 512 B per row
  const char* Bb = (const char*)(WT + (size_t)mat * 65536) + (size_t)col0 * 512;

  f32x4 acc[4][4] = {};

  for (int s = 0; s < 4; ++s) {
    int k0b = s * 128;                                                // 64 elems * 2B
#pragma unroll
    for (int j8 = 0; j8 < 4; ++j8) {
      int d = (j8 * 256 + tid) * 16;
      int row = d >> 7;
      int cx = (d & 127) ^ ((row & 7) << 4);                          // inverse swizzle on source
      glds16(Ab + (size_t)row * 512 + k0b + cx, Alds + d);
      glds16(Bb + (size_t)row * 512 + k0b + cx, Blds + d);
    }
    asm volatile("s_waitcnt vmcnt(0)" ::: "memory");
    __syncthreads();
#pragma unroll
    for (int ks = 0; ks < 2; ++ks) {
      short8 a[4], bb[4];
#pragma unroll
      for (int i = 0; i < 4; ++i) {
        int ra = wr + 16 * i + (l & 15);
        a[i] = *(const short8*)(Alds + ra * 128 + ((ks * 64 + hi16) ^ ((ra & 7) << 4)));
        int rb = wc + 16 * i + (l & 15);
        bb[i] = *(const short8*)(Blds + rb * 128 + ((ks * 64 + hi16) ^ ((rb & 7) << 4)));
      }
#pragma unroll
      for (int i = 0; i < 4; ++i)
#pragma unroll
        for (int j = 0; j < 4; ++j)
          acc[i][j] = __builtin_amdgcn_mfma_f32_16x16x32_bf16(a[i], bb[j], acc[i][j], 0, 0, 0);
    }
    __syncthreads();
  }

  // epilogue: C/D layout col = lane&15, row = (lane>>4)*4 + r  [m89]
  if constexpr (QKV) {
    if (mat < 2) {
      unsigned short* oq = (unsigned short*)out + (size_t)mat * M_ * 256;
#pragma unroll
      for (int i = 0; i < 4; ++i)
#pragma unroll
        for (int j = 0; j < 4; ++j)
#pragma unroll
          for (int r = 0; r < 4; ++r) {
            int row = rt * 128 + wr + 16 * i + (l >> 4) * 4 + r;
            int col = col0 + wc + 16 * j + (l & 15);
            oq[(size_t)row * 256 + col] = f2bf(acc[i][j][r]);
          }
    } else {
      // V: write transposed vT[b][feat][s]; 4 acc rows = 4 consecutive s -> 8B store
#pragma unroll
      for (int i = 0; i < 4; ++i) {
        int row0 = rt * 128 + wr + 16 * i + (l >> 4) * 4;             // multiple of 4
        int b = row0 >> 12, s0 = row0 & 4095;                         // tile never crosses batch
#pragma unroll
        for (int j = 0; j < 4; ++j) {
          int col = col0 + wc + 16 * j + (l & 15);
          us4 o;
#pragma unroll
          for (int r = 0; r < 4; ++r) o[r] = f2bf(acc[i][j][r]);
          *(us4*)(vT + ((size_t)(b * 256 + col) << 12) + s0) = o;
        }
      }
    }
  } else {
    float* of = (float*)out;
#pragma unroll
    for (int i = 0; i < 4; ++i)
#pragma unroll
      for (int j = 0; j < 4; ++j)
#pragma unroll
        for (int r = 0; r < 4; ++r) {
          int row = rt * 128 + wr + 16 * i + (l >> 4) * 4 + r;
          int col = col0 + wc + 16 * j + (l & 15);
          of[(size_t)row * 256 + col] = acc[i][j][r] + bias[col];
        }
  }
}

// ---------------- K2: block-local attention ----------------
// 1280 blocks: (b,n) x half. 4 waves x 16 q-rows. Q in regs; K/V chunks of 64 staged
// via swizzled-source global_load_lds; softmax without max-sub (|logit| < ~0.6, exact
// since softmax is shift-invariant); zero-padded edge chunks skipped (denominator +=
// exp(0)=1 per padded key).
__global__ __launch_bounds__(256, 2) void k_attn(const unsigned short* __restrict__ q,
                                                 const unsigned short* __restrict__ k,
                                                 const unsigned short* __restrict__ vT,
                                                 unsigned short* __restrict__ ob) {
  __shared__ char kv[32768];        // union: K chunk [64][256] / Vt chunk [256][64], swizzled
  __shared__ char pl[64 * 144];     // P [64 rows][64 keys] bf16, row stride 144 B

  int bx = blockIdx.x;
  int half = bx & 1, nbid = bx >> 1;
  int b = nbid >> 5, n = nbid & 31;
  int tid = threadIdx.x, w = tid >> 6, l = tid & 63;
  int hi16 = (l >> 4) * 16;

  // Q fragments: rows rowbase+(l&15), k-slices of 32
  int rowbase = b * 4096 + n * 128 + half * 64 + w * 16;
  const char* qrow = (const char*)q + (size_t)(rowbase + (l & 15)) * 512;
  short8 qf[8];
#pragma unroll
  for (int ks = 0; ks < 8; ++ks) qf[ks] = *(const short8*)(qrow + ks * 64 + hi16);

  f32x4 zero4 = {0.f, 0.f, 0.f, 0.f};
  f32x4 oacc[16];
#pragma unroll
  for (int fj = 0; fj < 16; ++fj) oacc[fj] = zero4;
  float dsum[4] = {0.f, 0.f, 0.f, 0.f};

  const char* kbase = (const char*)k + (size_t)b * 4096 * 512;
  const char* vtb   = (const char*)vT + (size_t)b * 256 * 8192;

  for (int c = 0; c < 6; ++c) {
    int nc = n + (c >> 1) - 1;                 // context block
    if (nc < 0 || nc > 31) {                   // zero-padded: exp(0)=1 per key, v=0
#pragma unroll
      for (int r = 0; r < 4; ++r) dsum[r] += 4.0f;   // 4 keys per lane per row
      continue;                                // block-uniform -> barrier counts stay uniform
    }
    int kg = nc * 128 + (c & 1) * 64;          // first key (s index within batch)

    __syncthreads();                           // kv buffer free (prev PV reads done)
#pragma unroll
    for (int j8 = 0; j8 < 8; ++j8) {           // stage K chunk: [64 keys][256 feats]
      int d = (j8 * 256 + tid) * 16;
      int key = d >> 9;
      int f2 = (d & 511) ^ ((key & 7) << 4);   // pre-swizzled source
      glds16(kbase + (size_t)(kg + key) * 512 + f2, kv + d);
    }
    asm volatile("s_waitcnt vmcnt(0)" ::: "memory");
    __syncthreads();

    // S = Q*K^T /16, exp, accumulate denom, P -> LDS (bf16)
#pragma unroll
    for (int j = 0; j < 4; ++j) {
      f32x4 s = zero4;
      int key = 16 * j + (l & 15);
      int kb0 = key * 512, km = (key & 7) << 4;
#pragma unroll
      for (int ks = 0; ks < 8; ++ks) {
        short8 kf = *(const short8*)(kv + kb0 + ((ks * 64 + hi16) ^ km));
        s = __builtin_amdgcn_mfma_f32_16x16x32_bf16(qf[ks], kf, s, 0, 0, 0);
      }
#pragma unroll
      for (int r = 0; r < 4; ++r) {
        float p = __expf(s[r] * 0.0625f);
        dsum[r] += p;
        int prow = w * 16 + (l >> 4) * 4 + r;
        *(unsigned short*)(pl + prow * 144 + key * 2) = f2bf(p);
      }
    }
    __syncthreads();                           // P written, K reads done

#pragma unroll
    for (int j8 = 0; j8 < 8; ++j8) {           // stage Vt chunk: [256 feats][64 keys]
      int d = (j8 * 256 + tid) * 16;
      int feat = d >> 7;
      int kx = (d & 127) ^ ((feat & 7) << 4);
      glds16(vtb + (size_t)feat * 8192 + (size_t)kg * 2 + kx, kv + d);
    }
    asm volatile("s_waitcnt vmcnt(0)" ::: "memory");
    __syncthreads();

    // O += P * V
#pragma unroll
    for (int ks2 = 0; ks2 < 2; ++ks2) {
      short8 pa = *(const short8*)(pl + (w * 16 + (l & 15)) * 144 + ks2 * 64 + hi16);
#pragma unroll
      for (int fj = 0; fj < 16; ++fj) {
        int feat = 16 * fj + (l & 15);
        short8 vf = *(const short8*)(kv + feat * 128 + ((ks2 * 64 + hi16) ^ ((feat & 7) << 4)));
        oacc[fj] = __builtin_amdgcn_mfma_f32_16x16x32_bf16(pa, vf, oacc[fj], 0, 0, 0);
      }
    }
  }

  // reduce denominator across the 16-lane column group
#pragma unroll
  for (int r = 0; r < 4; ++r) {
    float t = dsum[r];
    t += __shfl_xor(t, 1); t += __shfl_xor(t, 2);
    t += __shfl_xor(t, 4); t += __shfl_xor(t, 8);
    dsum[r] = 1.0f / t;
  }

  // write O/denom at PERMUTED rows: f = n*2560 + b*128 + qi
  int orow0 = n * 2560 + b * 128 + half * 64 + w * 16 + (l >> 4) * 4;
#pragma unroll
  for (int fj = 0; fj < 16; ++fj) {
    int col = 16 * fj + (l & 15);
#pragma unroll
    for (int r = 0; r < 4; ++r)
      ob[(size_t)(orow0 + r) * 256 + col] = f2bf(oacc[fj][r] * dsum[r]);
  }
}

// ---------------- launch ----------------
extern "C" void kernel_launch(void* const* d_in, const int* in_sizes, int n_in,
                              void* d_out, int out_size, void* d_ws, size_t ws_size,
                              hipStream_t stream) {
  (void)in_sizes; (void)n_in; (void)out_size; (void)ws_size;
  const float* x  = (const float*)d_in[0];
  const float* Wq = (const float*)d_in[1];
  const float* Wk = (const float*)d_in[2];
  const float* Wv = (const float*)d_in[3];
  const float* Wo = (const float*)d_in[4];
  const float* bo = (const float*)d_in[5];

  char* ws = (char*)d_ws;
  unsigned short* xb = (unsigned short*)ws;                  // reused as attention output ob
  unsigned short* qb = (unsigned short*)(ws + OFF_Q);        // q,k contiguous (mat*M*256)
  unsigned short* vT = (unsigned short*)(ws + OFF_V);
  unsigned short* WT = (unsigned short*)(ws + OFF_WT);
  unsigned short* kb = (unsigned short*)(ws + OFF_K);

  k_convert_x<<<20480, 256, 0, stream>>>(x, xb);
  k_convert_w<<<4, 256, 0, stream>>>(Wq, Wk, Wv, Wo, WT);
  k_gemm<true><<<3840, 256, 0, stream>>>(xb, WT, (void*)qb, vT, nullptr);  // q,k -> qb/kb; v -> vT
  k_attn<<<1280, 256, 0, stream>>>(qb, kb, vT, xb);                        // ob -> xb region
  k_gemm<false><<<1280, 256, 0, stream>>>(xb, WT, d_out, nullptr, bo);     // out = ob@Wo + bo
}

// Round 3
// 310.391 us; speedup vs baseline: 1.5094x; 1.5094x over previous
//
#include <hip/hip_runtime.h>
#include <stdint.h>

// Problem constants
#define B_   20
#define S_   4096
#define E_   256
#define NB_  32
#define M_   (B_ * S_)          // 81920 rows

// ws layout (bytes) — total ~168.3 MB
#define OFF_Q   41943040ull     // after xb/ob region (M*256*2)
#define OFF_K   83886080ull
#define OFF_V   125829120ull    // vT bf16 [B][E][S]
#define OFF_WT  167772160ull    // WqT,WkT,WvT,WoT bf16, 131072 B each

typedef __attribute__((ext_vector_type(4))) float f32x4;
typedef __attribute__((ext_vector_type(8))) short short8;   // 8 x bf16
typedef __attribute__((ext_vector_type(4))) float float4v;
typedef __attribute__((ext_vector_type(4))) unsigned short us4;

__device__ __forceinline__ unsigned short f2bf(float f) {
  unsigned int u = __builtin_bit_cast(unsigned int, f);
  u += 0x7FFFu + ((u >> 16) & 1u);            // RNE
  return (unsigned short)(u >> 16);
}

__device__ __forceinline__ void glds16(const void* g, void* l) {
  __builtin_amdgcn_global_load_lds(
      (const __attribute__((address_space(1))) unsigned int*)g,
      (__attribute__((address_space(3))) unsigned int*)l, 16, 0, 0);
}

// ---------------- K0a: x fp32 -> bf16 ----------------
__global__ void k_convert_x(const float* __restrict__ x, unsigned short* __restrict__ xb) {
  size_t id = (size_t)blockIdx.x * 256 + threadIdx.x;
  float4v v = *(const float4v*)(x + id * 4);
  us4 o;
  o[0] = f2bf(v[0]); o[1] = f2bf(v[1]); o[2] = f2bf(v[2]); o[3] = f2bf(v[3]);
  *(us4*)(xb + id * 4) = o;
}

// ---------------- K0b: weights fp32 -> bf16, TRANSPOSED ([n][k]) ----------------
__global__ void k_convert_w(const float* __restrict__ Wq, const float* __restrict__ Wk,
                            const float* __restrict__ Wv, const float* __restrict__ Wo,
                            unsigned short* __restrict__ WT) {
  const float* src = (blockIdx.x == 0) ? Wq : (blockIdx.x == 1) ? Wk
                   : (blockIdx.x == 2) ? Wv : Wo;
  unsigned short* dst = WT + (size_t)blockIdx.x * 65536;
  int n = threadIdx.x;
  for (int k = 0; k < 256; ++k)
    dst[n * 256 + k] = f2bf(src[k * 256 + n]);
}

// ---------------- K1/K3: GEMM, 2-phase pipelined, XCD-chunked swizzle ----------------
// 128x128 tile, BK=64, 4 waves each 64x64 (4x4 of 16x16x32 frags).
// LDS XOR-swizzled (byte ^= (row&7)<<4) via pre-swizzled global source (G21).
// mat==2 (V) epilogue writes transposed vT[b][feat][s].
template <bool QKV>
__global__ __launch_bounds__(256, 2) void k_gemm(const unsigned short* __restrict__ A,
                                                 const unsigned short* __restrict__ WT,
                                                 void* __restrict__ out,
                                                 unsigned short* __restrict__ vT,
                                                 const float* __restrict__ bias) {
  __shared__ char Alds[2][16384];
  __shared__ char Blds[2][16384];
  const int nct = QKV ? 6 : 2;
  // XCD-chunked: blocks sharing an A row-tile (same rt) land on the same XCD
  int g = blockIdx.x;
  int xcd = g & 7, idx = g >> 3;
  int rt = xcd * 80 + idx / nct;                 // 640 row-tiles, 80 per XCD
  int ct = idx % nct;
  int mat = QKV ? (ct >> 1) : 3;
  int col0 = (ct & 1) * 128;

  int tid = threadIdx.x, w = tid >> 6, l = tid & 63;
  int wr = (w >> 1) * 64, wc = (w & 1) * 64;
  int hi16 = (l >> 4) * 16;

  const char* Ab = (const char*)A + (size_t)rt * 128 * 512;
  const char* Bb = (const char*)(WT + (size_t)mat * 65536) + (size_t)col0 * 512;

  auto STAGE = [&](int bufi, int s) {
    int k0b = s * 128;
#pragma unroll
    for (int j8 = 0; j8 < 4; ++j8) {
      int d = (j8 * 256 + tid) * 16;
      int row = d >> 7;
      int cx = (d & 127) ^ ((row & 7) << 4);
      glds16(Ab + (size_t)row * 512 + k0b + cx, Alds[bufi] + d);
      glds16(Bb + (size_t)row * 512 + k0b + cx, Blds[bufi] + d);
    }
  };

  f32x4 acc[4][4] = {};
  STAGE(0, 0);

  for (int s = 0; s < 4; ++s) {
    int cur = s & 1;
    if (s < 3) {
      STAGE(cur ^ 1, s + 1);
      asm volatile("s_waitcnt vmcnt(8)" ::: "memory");   // current stage's 8 loads landed
    } else {
      asm volatile("s_waitcnt vmcnt(0)" ::: "memory");
    }
    __builtin_amdgcn_sched_barrier(0);
    __builtin_amdgcn_s_barrier();
#pragma unroll
    for (int ks = 0; ks < 2; ++ks) {
      short8 a[4], bb[4];
#pragma unroll
      for (int i = 0; i < 4; ++i) {
        int ra = wr + 16 * i + (l & 15);
        a[i] = *(const short8*)(Alds[cur] + ra * 128 + ((ks * 64 + hi16) ^ ((ra & 7) << 4)));
        int rb = wc + 16 * i + (l & 15);
        bb[i] = *(const short8*)(Blds[cur] + rb * 128 + ((rb & 7) << 4 ^ (ks * 64 + hi16)));
      }
      __builtin_amdgcn_s_setprio(1);
#pragma unroll
      for (int i = 0; i < 4; ++i)
#pragma unroll
        for (int j = 0; j < 4; ++j)
          acc[i][j] = __builtin_amdgcn_mfma_f32_16x16x32_bf16(a[i], bb[j], acc[i][j], 0, 0, 0);
      __builtin_amdgcn_s_setprio(0);
    }
    asm volatile("s_waitcnt lgkmcnt(0)" ::: "memory");
    __builtin_amdgcn_sched_barrier(0);
    __builtin_amdgcn_s_barrier();                        // buffer free for next STAGE
  }

  // epilogue: C/D layout col = lane&15, row = (lane>>4)*4 + r  [m89]
  if constexpr (QKV) {
    if (mat < 2) {
      unsigned short* oq = (unsigned short*)out + (size_t)mat * M_ * 256;
#pragma unroll
      for (int i = 0; i < 4; ++i)
#pragma unroll
        for (int j = 0; j < 4; ++j)
#pragma unroll
          for (int r = 0; r < 4; ++r) {
            int row = rt * 128 + wr + 16 * i + (l >> 4) * 4 + r;
            int col = col0 + wc + 16 * j + (l & 15);
            oq[(size_t)row * 256 + col] = f2bf(acc[i][j][r]);
          }
    } else {
      // V: write transposed vT[b][feat][s]; 4 acc rows = 4 consecutive s -> 8B store
#pragma unroll
      for (int i = 0; i < 4; ++i) {
        int row0 = rt * 128 + wr + 16 * i + (l >> 4) * 4;
        int b = row0 >> 12, s0 = row0 & 4095;
#pragma unroll
        for (int j = 0; j < 4; ++j) {
          int col = col0 + wc + 16 * j + (l & 15);
          us4 o;
#pragma unroll
          for (int r = 0; r < 4; ++r) o[r] = f2bf(acc[i][j][r]);
          *(us4*)(vT + ((size_t)(b * 256 + col) << 12) + s0) = o;
        }
      }
    }
  } else {
    float* of = (float*)out;
#pragma unroll
    for (int i = 0; i < 4; ++i)
#pragma unroll
      for (int j = 0; j < 4; ++j)
#pragma unroll
        for (int r = 0; r < 4; ++r) {
          int row = rt * 128 + wr + 16 * i + (l >> 4) * 4 + r;
          int col = col0 + wc + 16 * j + (l & 15);
          of[(size_t)row * 256 + col] = acc[i][j][r] + bias[col];
        }
  }
}

// ---------------- K2: block-local attention, 2-buffer pipelined ----------------
// Phase sequence per block: for each valid 64-key chunk c: {K-phase: QK^T+exp+P,
// V-phase: PV}. Prefetch phase p+1 into buf[(p+1)&1] while computing p; counted
// vmcnt(8); raw s_barrier (no vmcnt(0) drain mid-loop). P-tile is wave-private.
// Softmax without max-sub (|logit| < ~0.6, exact by shift-invariance); padded edge
// chunks contribute exp(0)=1 per key -> dsum preinit.
__global__ __launch_bounds__(256, 2) void k_attn(const unsigned short* __restrict__ q,
                                                 const unsigned short* __restrict__ k,
                                                 const unsigned short* __restrict__ vT,
                                                 unsigned short* __restrict__ ob) {
  __shared__ char kb2[2][32768];    // K chunk [64][256] or Vt chunk [256][64], swizzled
  __shared__ char pl[64 * 144];     // P [64 rows][64 keys] bf16, row stride 144 B

  // XCD-chunked: consecutive (b,n) share 2/3 of K/V context -> same XCD L2
  int g = blockIdx.x;
  int xcd = g & 7, idx = g >> 3;                 // 160 per XCD
  int nbid = xcd * 80 + (idx >> 1);
  int half = idx & 1;
  int b = nbid >> 5, n = nbid & 31;
  int tid = threadIdx.x, w = tid >> 6, l = tid & 63;
  int hi16 = (l >> 4) * 16;

  int rowbase = b * 4096 + n * 128 + half * 64 + w * 16;
  const char* qrow = (const char*)q + (size_t)(rowbase + (l & 15)) * 512;
  short8 qf[8];
#pragma unroll
  for (int ks = 0; ks < 8; ++ks) qf[ks] = *(const short8*)(qrow + ks * 64 + hi16);

  f32x4 zero4 = {0.f, 0.f, 0.f, 0.f};
  f32x4 oacc[16];
#pragma unroll
  for (int fj = 0; fj < 16; ++fj) oacc[fj] = zero4;
  // padded-edge chunks (2 at n=0 or n=31) contribute exp(0)=1 per key: 2*4 per lane/row
  float einit = (n == 0 || n == 31) ? 8.0f : 0.0f;
  float dsum[4] = {einit, einit, einit, einit};

  const char* kbase = (const char*)k + (size_t)b * 4096 * 512;
  const char* vtb   = (const char*)vT + (size_t)b * 256 * 8192;

  int c0 = (n == 0) ? 2 : 0;                     // valid chunk range (contiguous)
  int c1 = (n == 31) ? 3 : 5;
  int P = (c1 - c0 + 1) * 2;                     // 8 or 12 phases

  auto STAGE = [&](int bufi, int p) {
    int c = c0 + (p >> 1);
    int kg = (n + (c >> 1) - 1) * 128 + (c & 1) * 64;
    char* dst = kb2[bufi];
    if ((p & 1) == 0) {                          // K chunk: [64 keys][256 feats]
#pragma unroll
      for (int j8 = 0; j8 < 8; ++j8) {
        int d = (j8 * 256 + tid) * 16;
        int key = d >> 9;
        int f2 = (d & 511) ^ ((key & 7) << 4);
        glds16(kbase + (size_t)(kg + key) * 512 + f2, dst + d);
      }
    } else {                                     // Vt chunk: [256 feats][64 keys]
#pragma unroll
      for (int j8 = 0; j8 < 8; ++j8) {
        int d = (j8 * 256 + tid) * 16;
        int feat = d >> 7;
        int kx = (d & 127) ^ ((feat & 7) << 4);
        glds16(vtb + (size_t)feat * 8192 + (size_t)kg * 2 + kx, dst + d);
      }
    }
  };

  STAGE(0, 0);

  for (int p = 0; p < P; ++p) {
    int cur = p & 1;
    if (p + 1 < P) {
      STAGE(cur ^ 1, p + 1);
      asm volatile("s_waitcnt vmcnt(8)" ::: "memory");   // phase p's 8 loads landed
    } else {
      asm volatile("s_waitcnt vmcnt(0)" ::: "memory");
    }
    __builtin_amdgcn_sched_barrier(0);
    __builtin_amdgcn_s_barrier();

    const char* kv = kb2[cur];
    if ((p & 1) == 0) {
      // QK^T /16, exp, denom, P -> LDS
#pragma unroll
      for (int j = 0; j < 4; ++j) {
        f32x4 s = zero4;
        int key = 16 * j + (l & 15);
        int kb0 = key * 512, km = (key & 7) << 4;
        __builtin_amdgcn_s_setprio(1);
#pragma unroll
        for (int ks = 0; ks < 8; ++ks) {
          short8 kf = *(const short8*)(kv + kb0 + ((ks * 64 + hi16) ^ km));
          s = __builtin_amdgcn_mfma_f32_16x16x32_bf16(qf[ks], kf, s, 0, 0, 0);
        }
        __builtin_amdgcn_s_setprio(0);
#pragma unroll
        for (int r = 0; r < 4; ++r) {
          float pv = __expf(s[r] * 0.0625f);
          dsum[r] += pv;
          int prow = w * 16 + (l >> 4) * 4 + r;
          *(unsigned short*)(pl + prow * 144 + key * 2) = f2bf(pv);
        }
      }
    } else {
      // O += P * V
#pragma unroll
      for (int ks2 = 0; ks2 < 2; ++ks2) {
        short8 pa = *(const short8*)(pl + (w * 16 + (l & 15)) * 144 + ks2 * 64 + hi16);
        __builtin_amdgcn_s_setprio(1);
#pragma unroll
        for (int fj = 0; fj < 16; ++fj) {
          int feat = 16 * fj + (l & 15);
          short8 vf = *(const short8*)(kv + feat * 128 + ((ks2 * 64 + hi16) ^ ((feat & 7) << 4)));
          oacc[fj] = __builtin_amdgcn_mfma_f32_16x16x32_bf16(pa, vf, oacc[fj], 0, 0, 0);
        }
        __builtin_amdgcn_s_setprio(0);
      }
    }
    asm volatile("s_waitcnt lgkmcnt(0)" ::: "memory");
    __builtin_amdgcn_sched_barrier(0);
    __builtin_amdgcn_s_barrier();                        // buffer free for next STAGE
  }

  // reduce denominator across the 16-lane column group
#pragma unroll
  for (int r = 0; r < 4; ++r) {
    float t = dsum[r];
    t += __shfl_xor(t, 1); t += __shfl_xor(t, 2);
    t += __shfl_xor(t, 4); t += __shfl_xor(t, 8);
    dsum[r] = 1.0f / t;
  }

  // write O/denom at PERMUTED rows: f = n*2560 + b*128 + qi
  int orow0 = n * 2560 + b * 128 + half * 64 + w * 16 + (l >> 4) * 4;
#pragma unroll
  for (int fj = 0; fj < 16; ++fj) {
    int col = 16 * fj + (l & 15);
#pragma unroll
    for (int r = 0; r < 4; ++r)
      ob[(size_t)(orow0 + r) * 256 + col] = f2bf(oacc[fj][r] * dsum[r]);
  }
}

// ---------------- launch ----------------
extern "C" void kernel_launch(void* const* d_in, const int* in_sizes, int n_in,
                              void* d_out, int out_size, void* d_ws, size_t ws_size,
                              hipStream_t stream) {
  (void)in_sizes; (void)n_in; (void)out_size; (void)ws_size;
  const float* x  = (const float*)d_in[0];
  const float* Wq = (const float*)d_in[1];
  const float* Wk = (const float*)d_in[2];
  const float* Wv = (const float*)d_in[3];
  const float* Wo = (const float*)d_in[4];
  const float* bo = (const float*)d_in[5];

  char* ws = (char*)d_ws;
  unsigned short* xb = (unsigned short*)ws;                  // reused as attention output ob
  unsigned short* qb = (unsigned short*)(ws + OFF_Q);        // q,k contiguous (mat*M*256)
  unsigned short* kb = (unsigned short*)(ws + OFF_K);
  unsigned short* vT = (unsigned short*)(ws + OFF_V);
  unsigned short* WT = (unsigned short*)(ws + OFF_WT);

  k_convert_x<<<20480, 256, 0, stream>>>(x, xb);
  k_convert_w<<<4, 256, 0, stream>>>(Wq, Wk, Wv, Wo, WT);
  k_gemm<true><<<3840, 256, 0, stream>>>(xb, WT, (void*)qb, vT, nullptr);  // q,k -> qb/kb; v -> vT
  k_attn<<<1280, 256, 0, stream>>>(qb, kb, vT, xb);                        // ob -> xb region
  k_gemm<false><<<1280, 256, 0, stream>>>(xb, WT, d_out, nullptr, bo);     // out = ob@Wo + bo
}